// Round 16
// baseline (1727.677 us; speedup 1.0000x reference)
//
#include <hip/hip_runtime.h>

#define HH 128
#define TT 1024
#define NFUT 64
#define MB 2
#define NBLK 256
#define NITER (TT + NFUT - 1)  // i=1023 -> out[0], i=1086 -> out[63]

typedef _Float16 half8 __attribute__((ext_vector_type(8)));
typedef float floatx4 __attribute__((ext_vector_type(4)));

#define MFMA16(a, b, c) __builtin_amdgcn_mfma_f32_16x16x32_f16((a), (b), (c), 0, 0, 0)

__device__ __forceinline__ float sigm(float v) {
  return __builtin_amdgcn_rcpf(1.0f + __builtin_amdgcn_exp2f(v * -1.442695040888963f));
}
__device__ __forceinline__ float tanh_f(float v) {
  float a = __builtin_fabsf(v);
  float e = __builtin_amdgcn_exp2f(a * -2.885390081777927f);
  float r = (1.0f - e) * __builtin_amdgcn_rcpf(1.0f + e);
  return __builtin_copysignf(r, v);
}
__device__ __forceinline__ half8 ldw8(const float* __restrict__ p) {
  half8 r;
#pragma unroll
  for (int i = 0; i < 8; ++i) r[i] = (_Float16)p[i];
  return r;
}

// Persistent 2-layer LSTM, 256 WG x 512 thr (8 waves), MB=2 rows/WG.
// == r8 champion structure (sequential, 1 barrier/encoder step, post-MFMA
// bias, loop-end sched_barrier) + two VALU-count cuts ==
//
// REGISTER LAW (r1-r15): per-wave total budget = 512/(waves/SIMD), split
// ~half arch / half AGPR; VALU reads arch only; MFMA B reads AGPR natively.
// 8 waves (2/SIMD) is the unique config where the 192-reg weight set is
// resident (128 AGPR + 64 arch). Sequential {P1} B {P2} keeps acc sets in
// separate scheduling regions -> no spill. DO NOT FUSE PHASES (r9-r13).
//
// THIS ROUND (counter evidence: MfmaUtil 45 + VALUBusy 53 ~ 98%, pipes
// alternate; shrink the VALU segment):
//  (1) opaque-zero C-in (zc laundered into AGPRs once): kf=0 MFMA of each
//      gate uses C=zc -> kills 32 v_accvgpr_write zero-inits per iter.
//  (2) 32-lane finalize: one shfl_xor(16) per gate moves row1 onto lanes
//      16-31 -> each lane runs ONE transcendental chain instead of lanes
//      0-15 running two. Extraction count unchanged (8 acc reads/phase).
__global__
__attribute__((amdgpu_flat_work_group_size(512, 512), amdgpu_waves_per_eu(2, 2)))
void lstm_kernel(
    const float* __restrict__ x,
    const float* __restrict__ W_ih1, const float* __restrict__ b_ih1,
    const float* __restrict__ W_hh1, const float* __restrict__ b_hh1,
    const float* __restrict__ W_ih2, const float* __restrict__ b_ih2,
    const float* __restrict__ W_hh2, const float* __restrict__ b_hh2,
    const float* __restrict__ W_out, const float* __restrict__ b_out,
    float* __restrict__ out)
{
  __shared__ __align__(16) _Float16 h1b[2][2048];  // A-frag order; rows>=MB stay 0
  __shared__ __align__(16) _Float16 h2b[2][2048];
  __shared__ __align__(16) _Float16 xs[TT * MB];   // [t][b]
  __shared__ float opart[8 * MB];

  const int tid = (int)threadIdx.x;
  const int lane = tid & 63;
  const int w = tid >> 6;
  const int jl = lane & 15;
  const int rg = lane >> 4;
  const int j = w * 16 + jl;
  const int b0g = (int)blockIdx.x * MB;

  for (int idx = tid; idx < TT * MB; idx += 512) {
    int t = idx & (TT - 1);
    int bb = idx >> 10;
    xs[t * MB + bb] = (_Float16)x[(b0g + bb) * TT + t];
  }
  for (int idx = tid; idx < 2 * 2048; idx += 512) {
    h1b[idx >> 11][idx & 2047] = (_Float16)0.0f;
    h2b[idx >> 11][idx & 2047] = (_Float16)0.0f;
  }

  // ---- 48 named weight B-fragments: A=W_hh1, H=W_hh2, I=W_ih2 ----
  half8 A00, A01, A02, A03, A10, A11, A12, A13, A20, A21, A22, A23, A30, A31, A32, A33;
  half8 H00, H01, H02, H03, H10, H11, H12, H13, H20, H21, H22, H23, H30, H31, H32, H33;
  half8 I00, I01, I02, I03, I10, I11, I12, I13, I20, I21, I22, I23, I30, I31, I32, I33;
#define LDW(N, Q, P) do { \
    const float* _p = (P) + ((Q) * HH + j) * HH + rg * 8; \
    N##0 = ldw8(_p);      N##1 = ldw8(_p + 32); \
    N##2 = ldw8(_p + 64); N##3 = ldw8(_p + 96); } while (0)
  LDW(A0, 0, W_hh1); LDW(A1, 1, W_hh1); LDW(A2, 2, W_hh1); LDW(A3, 3, W_hh1);
  LDW(H0, 0, W_hh2); LDW(H1, 1, W_hh2); LDW(H2, 2, W_hh2); LDW(H3, 3, W_hh2);
  LDW(I0, 0, W_ih2); LDW(I1, 1, W_ih2); LDW(I2, 2, W_ih2); LDW(I3, 3, W_ih2);

  float bias1[4], bias2[4], wi1[4];
#pragma unroll
  for (int q = 0; q < 4; ++q) {
    bias1[q] = b_ih1[q * HH + j] + b_hh1[q * HH + j];
    bias2[q] = b_ih2[q * HH + j] + b_hh2[q * HH + j];
    wi1[q] = W_ih1[q * HH + j];
  }
  const float wo = W_out[j];
  const float bo = b_out[0];
  // one c per lane per cell: lane<16 -> row0, lane 16-31 -> row1 (32-63 junk)
  float c1 = 0.f, c2 = 0.f;

  // opaque zeros, parked in AGPRs once: C-in for every kf=0 MFMA
  floatx4 zc = {0.f, 0.f, 0.f, 0.f};
  asm("" : "+a"(zc));

  __syncthreads();

  const int aoff = lane * 8;
  const int wb = ((j >> 5) << 9) + (((j >> 3) & 3) << 7) + (j & 7);
  const int rowq = (lane >> 4) & 1;          // row this lane finalizes (0-31)
  const int wbR = wb + (rowq << 3);          // h LDS slot incl. row offset

  // kf=0 bursts seed from zc (no acc zero-init); kf=1..3 accumulate
#define G1K0() do { \
    half8 av = *(const half8*)(&h1b[cur][aoff]); \
    p0 = MFMA16(av, A00, zc); p1 = MFMA16(av, A10, zc); \
    p2 = MFMA16(av, A20, zc); p3 = MFMA16(av, A30, zc); } while (0)
#define G1K(KF) do { \
    half8 av = *(const half8*)(&h1b[cur][KF * 512 + aoff]); \
    p0 = MFMA16(av, A0##KF, p0); p1 = MFMA16(av, A1##KF, p1); \
    p2 = MFMA16(av, A2##KF, p2); p3 = MFMA16(av, A3##KF, p3); } while (0)
#define G2K0() do { \
    half8 av = *(const half8*)(&h2b[cur][aoff]); \
    p0 = MFMA16(av, H00, zc); p1 = MFMA16(av, H10, zc); \
    p2 = MFMA16(av, H20, zc); p3 = MFMA16(av, H30, zc); \
    half8 aw = *(const half8*)(&h1b[nxt][aoff]); \
    p0 = MFMA16(aw, I00, p0); p1 = MFMA16(aw, I10, p1); \
    p2 = MFMA16(aw, I20, p2); p3 = MFMA16(aw, I30, p3); } while (0)
#define G2K(KF) do { \
    half8 av = *(const half8*)(&h2b[cur][KF * 512 + aoff]); \
    p0 = MFMA16(av, H0##KF, p0); p1 = MFMA16(av, H1##KF, p1); \
    p2 = MFMA16(av, H2##KF, p2); p3 = MFMA16(av, H3##KF, p3); \
    half8 aw = *(const half8*)(&h1b[nxt][KF * 512 + aoff]); \
    p0 = MFMA16(aw, I0##KF, p0); p1 = MFMA16(aw, I1##KF, p1); \
    p2 = MFMA16(aw, I2##KF, p2); p3 = MFMA16(aw, I3##KF, p3); } while (0)

  for (int i = 0; i < NITER; ++i) {
    const int cur = i & 1;
    const int nxt = cur ^ 1;

    // ---- x for this step, per-lane row rowq ----
    float xb;
    if (i < TT) {
      xb = (float)xs[i * MB + rowq];
    } else {
      float s = bo;
#pragma unroll
      for (int p = 0; p < 8; ++p) s += opart[p * MB + rowq];
      xb = s;
    }

    // ---- phase 1: gates1 = h1(i-1) @ W_hh1^T ----
    floatx4 p0, p1, p2, p3;
    G1K0(); G1K(1); G1K(2); G1K(3);
    {
      // move row1 gate values to lanes 16-31 (one shfl per gate)
      float ri = __shfl_xor(p0[1], 16);
      float rf = __shfl_xor(p1[1], 16);
      float rgg = __shfl_xor(p2[1], 16);
      float ro = __shfl_xor(p3[1], 16);
      const bool hi = (lane & 16) != 0;
      float gi = (hi ? ri : p0[0]) + xb * wi1[0] + bias1[0];
      float gf = (hi ? rf : p1[0]) + xb * wi1[1] + bias1[1];
      float gg = (hi ? rgg : p2[0]) + xb * wi1[2] + bias1[2];
      float go = (hi ? ro : p3[0]) + xb * wi1[3] + bias1[3];
      c1 = sigm(gf) * c1 + sigm(gi) * tanh_f(gg);
      float h = sigm(go) * tanh_f(c1);
      if (lane < 32) h1b[nxt][wbR] = (_Float16)h;
    }
    __syncthreads();  // the ONE barrier: publishes h1(i)

    // ---- phase 2: gates2 = h2(i-1)@W_hh2^T + h1(i)@W_ih2^T ----
    G2K0(); G2K(1); G2K(2); G2K(3);
    {
      float ri = __shfl_xor(p0[1], 16);
      float rf = __shfl_xor(p1[1], 16);
      float rgg = __shfl_xor(p2[1], 16);
      float ro = __shfl_xor(p3[1], 16);
      const bool hi = (lane & 16) != 0;
      float gi = (hi ? ri : p0[0]) + bias2[0];
      float gf = (hi ? rf : p1[0]) + bias2[1];
      float gg = (hi ? rgg : p2[0]) + bias2[2];
      float go = (hi ? ro : p3[0]) + bias2[3];
      c2 = sigm(gf) * c2 + sigm(gi) * tanh_f(gg);
      float h = sigm(go) * tanh_f(c2);
      if (lane < 32) h2b[nxt][wbR] = (_Float16)h;
      if (i >= TT - 1) {
        // projection partials: reduce h*wo over the 16 lanes of each row group
        float q = h * wo;
        q += __shfl_xor(q, 1);
        q += __shfl_xor(q, 2);
        q += __shfl_xor(q, 4);
        q += __shfl_xor(q, 8);
        if ((lane & 15) == 0 && lane < 32) opart[w * MB + rowq] = q;
      }
    }

    if (i >= TT - 1) {
      __syncthreads();  // publish opart (future feedback + out write)
      if (w == 0 && (lane & 15) == 0 && lane < 32) {
        float s = bo;
#pragma unroll
        for (int p = 0; p < 8; ++p) s += opart[p * MB + rowq];
        out[(b0g + rowq) * NFUT + (i - (TT - 1))] = s;
      }
    }
    // pin the P2 -> P1(i+1) seam across the backedge (no-spill discipline)
    __builtin_amdgcn_sched_barrier(0);
  }
}

extern "C" void kernel_launch(void* const* d_in, const int* in_sizes, int n_in,
                              void* d_out, int out_size, void* d_ws, size_t ws_size,
                              hipStream_t stream) {
  const float* x     = (const float*)d_in[0];
  const float* W_ih1 = (const float*)d_in[1];
  const float* b_ih1 = (const float*)d_in[2];
  const float* W_hh1 = (const float*)d_in[3];
  const float* b_hh1 = (const float*)d_in[4];
  const float* W_ih2 = (const float*)d_in[5];
  const float* b_ih2 = (const float*)d_in[6];
  const float* W_hh2 = (const float*)d_in[7];
  const float* b_hh2 = (const float*)d_in[8];
  const float* W_out = (const float*)d_in[9];
  const float* b_out = (const float*)d_in[10];
  (void)in_sizes; (void)n_in; (void)out_size; (void)d_ws; (void)ws_size;

  lstm_kernel<<<dim3(NBLK), dim3(512), 0, stream>>>(
      x, W_ih1, b_ih1, W_hh1, b_hh1, W_ih2, b_ih2, W_hh2, b_hh2, W_out, b_out,
      (float*)d_out);
}

// Round 17
// 1636.274 us; speedup vs baseline: 1.0559x; 1.0559x over previous
//
#include <hip/hip_runtime.h>

#define HH 128
#define TT 1024
#define NFUT 64
#define MB 2
#define NBLK 256
#define NITER (TT + NFUT)  // k=0..1087; iter k computes h1(k) and h2(k-1)

typedef _Float16 half8 __attribute__((ext_vector_type(8)));
typedef float floatx4 __attribute__((ext_vector_type(4)));

#define MFMA16(a, b, c) __builtin_amdgcn_mfma_f32_16x16x32_f16((a), (b), (c), 0, 0, 0)

__device__ __forceinline__ float sigm(float v) {
  return __builtin_amdgcn_rcpf(1.0f + __builtin_amdgcn_exp2f(v * -1.442695040888963f));
}
__device__ __forceinline__ float tanh_f(float v) {
  float a = __builtin_fabsf(v);
  float e = __builtin_amdgcn_exp2f(a * -2.885390081777927f);
  float r = (1.0f - e) * __builtin_amdgcn_rcpf(1.0f + e);
  return __builtin_copysignf(r, v);
}
__device__ __forceinline__ half8 ldw8(const float* __restrict__ p) {
  half8 r;
#pragma unroll
  for (int i = 0; i < 8; ++i) r[i] = (_Float16)p[i];
  return r;
}

// Persistent 2-layer LSTM, 256 WG x 512 thr (8 waves), MB=2 rows/WG.
// == champion (1523us) math + ANTI-PHASE wave-group order swap ==
//
// Champion signature: MfmaUtil 45 + VALUBusy 53 ~= 98% -> XDL and VALU run
// serially because both waves/SIMD are locked into the same phase. Fix:
// cell1(k) and cell2(k-1) are independent (both read only pre-iter state;
// r9 race audit). Two barrier-separated regions per iter, OPPOSITE order by
// wave group (HW: wave w -> SIMD w%4, so waves w and w+4 share a SIMD):
//   waves 0-3: R1{cell1(k)}   B1  R2{cell2(k-1)}   B2
//   waves 4-7: R1{cell2(k-1)} B1  R2{cell1(k)}     B2
// -> in each region one wave bursts MFMA while the partner's finalize VALU
// overlaps. One acc set live per region (champion register shape, no fusion
// -> no spill). setprio(1) around bursts (role diversity now exists).
// Future iters (64): sequential fallback (x-feedback needs all-wave h2):
//   R1{cell2(k-1)+proj} B1 R2{x=sum(opart); out; cell1(k)} B2.
//
// Buffers: h1(k) -> h1b[k&1]; h2(k-1) -> h2b[(k-1)&1]. Iter k reads
// h1b[prv]=h1(k-1), h2b[cur]=h2(k-2); writes h1b[cur], h2b[prv] (disjoint).
// Cross-iter write->read pairs all separated by B2. REGISTER LAW (r1-r16):
// only 8 waves @ 2/SIMD fits the 192-reg weight set (128 AGPR + 64 arch);
// accs zero-init (AGPR residency); bias/x added post-MFMA.
__global__
__attribute__((amdgpu_flat_work_group_size(512, 512), amdgpu_waves_per_eu(2, 2)))
void lstm_kernel(
    const float* __restrict__ x,
    const float* __restrict__ W_ih1, const float* __restrict__ b_ih1,
    const float* __restrict__ W_hh1, const float* __restrict__ b_hh1,
    const float* __restrict__ W_ih2, const float* __restrict__ b_ih2,
    const float* __restrict__ W_hh2, const float* __restrict__ b_hh2,
    const float* __restrict__ W_out, const float* __restrict__ b_out,
    float* __restrict__ out)
{
  __shared__ __align__(16) _Float16 h1b[2][2048];  // A-frag order; rows>=MB stay 0
  __shared__ __align__(16) _Float16 h2b[2][2048];
  __shared__ __align__(16) _Float16 xs[TT * MB];   // [t][b]
  __shared__ float opart[8 * MB];

  const int tid = (int)threadIdx.x;
  const int lane = tid & 63;
  const int w = tid >> 6;
  const int jl = lane & 15;
  const int rg = lane >> 4;
  const int j = w * 16 + jl;
  const int b0g = (int)blockIdx.x * MB;

  for (int idx = tid; idx < TT * MB; idx += 512) {
    int t = idx & (TT - 1);
    int bb = idx >> 10;
    xs[t * MB + bb] = (_Float16)x[(b0g + bb) * TT + t];
  }
  for (int idx = tid; idx < 2 * 2048; idx += 512) {
    h1b[idx >> 11][idx & 2047] = (_Float16)0.0f;
    h2b[idx >> 11][idx & 2047] = (_Float16)0.0f;
  }

  // ---- 48 named weight B-fragments: A=W_hh1, H=W_hh2, I=W_ih2 ----
  half8 A00, A01, A02, A03, A10, A11, A12, A13, A20, A21, A22, A23, A30, A31, A32, A33;
  half8 H00, H01, H02, H03, H10, H11, H12, H13, H20, H21, H22, H23, H30, H31, H32, H33;
  half8 I00, I01, I02, I03, I10, I11, I12, I13, I20, I21, I22, I23, I30, I31, I32, I33;
#define LDW(N, Q, P) do { \
    const float* _p = (P) + ((Q) * HH + j) * HH + rg * 8; \
    N##0 = ldw8(_p);      N##1 = ldw8(_p + 32); \
    N##2 = ldw8(_p + 64); N##3 = ldw8(_p + 96); } while (0)
  LDW(A0, 0, W_hh1); LDW(A1, 1, W_hh1); LDW(A2, 2, W_hh1); LDW(A3, 3, W_hh1);
  LDW(H0, 0, W_hh2); LDW(H1, 1, W_hh2); LDW(H2, 2, W_hh2); LDW(H3, 3, W_hh2);
  LDW(I0, 0, W_ih2); LDW(I1, 1, W_ih2); LDW(I2, 2, W_ih2); LDW(I3, 3, W_ih2);

  float bias1[4], bias2[4], wi1[4];
#pragma unroll
  for (int q = 0; q < 4; ++q) {
    bias1[q] = b_ih1[q * HH + j] + b_hh1[q * HH + j];
    bias2[q] = b_ih2[q * HH + j] + b_hh2[q * HH + j];
    wi1[q] = W_ih1[q * HH + j];
  }
  const float wo = W_out[j];
  const float bo = b_out[0];
  float c1a = 0.f, c1b = 0.f, c2a = 0.f, c2b = 0.f;  // lanes 0-15 meaningful

  __syncthreads();

  const int aoff = lane * 8;
  const int wb = ((j >> 5) << 9) + (((j >> 3) & 3) << 7) + (j & 7);

#define G1K(KF) do { \
    half8 av = *(const half8*)(&h1b[prv][KF * 512 + aoff]); \
    p0 = MFMA16(av, A0##KF, p0); p1 = MFMA16(av, A1##KF, p1); \
    p2 = MFMA16(av, A2##KF, p2); p3 = MFMA16(av, A3##KF, p3); } while (0)
#define G2K(KF) do { \
    half8 av = *(const half8*)(&h2b[cur][KF * 512 + aoff]); \
    p0 = MFMA16(av, H0##KF, p0); p1 = MFMA16(av, H1##KF, p1); \
    p2 = MFMA16(av, H2##KF, p2); p3 = MFMA16(av, H3##KF, p3); \
    half8 aw = *(const half8*)(&h1b[prv][KF * 512 + aoff]); \
    p0 = MFMA16(aw, I0##KF, p0); p1 = MFMA16(aw, I1##KF, p1); \
    p2 = MFMA16(aw, I2##KF, p2); p3 = MFMA16(aw, I3##KF, p3); } while (0)

  // cell1(k): reads h1b[prv], writes h1b[cur]; x enters post-MFMA
#define CELL1(X0, X1) do { \
    floatx4 p0 = {0.f,0.f,0.f,0.f}, p1 = {0.f,0.f,0.f,0.f}; \
    floatx4 p2 = {0.f,0.f,0.f,0.f}, p3 = {0.f,0.f,0.f,0.f}; \
    __builtin_amdgcn_s_setprio(1); \
    G1K(0); G1K(1); G1K(2); G1K(3); \
    __builtin_amdgcn_s_setprio(0); \
    float gi0 = p0[0] + (X0) * wi1[0] + bias1[0], gi1 = p0[1] + (X1) * wi1[0] + bias1[0]; \
    float gf0 = p1[0] + (X0) * wi1[1] + bias1[1], gf1 = p1[1] + (X1) * wi1[1] + bias1[1]; \
    float gg0 = p2[0] + (X0) * wi1[2] + bias1[2], gg1 = p2[1] + (X1) * wi1[2] + bias1[2]; \
    float go0 = p3[0] + (X0) * wi1[3] + bias1[3], go1 = p3[1] + (X1) * wi1[3] + bias1[3]; \
    c1a = sigm(gf0) * c1a + sigm(gi0) * tanh_f(gg0); \
    c1b = sigm(gf1) * c1b + sigm(gi1) * tanh_f(gg1); \
    float h10 = sigm(go0) * tanh_f(c1a); \
    float h11 = sigm(go1) * tanh_f(c1b); \
    if (lane < 16) { \
      h1b[cur][wb] = (_Float16)h10; \
      h1b[cur][wb + 8] = (_Float16)h11; \
    } } while (0)

  // cell2(k-1): reads h2b[cur]=h2(k-2), h1b[prv]=h1(k-1); writes h2b[prv]
#define CELL2(DOPROJ) do { \
    floatx4 p0 = {0.f,0.f,0.f,0.f}, p1 = {0.f,0.f,0.f,0.f}; \
    floatx4 p2 = {0.f,0.f,0.f,0.f}, p3 = {0.f,0.f,0.f,0.f}; \
    __builtin_amdgcn_s_setprio(1); \
    G2K(0); G2K(1); G2K(2); G2K(3); \
    __builtin_amdgcn_s_setprio(0); \
    float gi0 = p0[0] + bias2[0], gi1 = p0[1] + bias2[0]; \
    float gf0 = p1[0] + bias2[1], gf1 = p1[1] + bias2[1]; \
    float gg0 = p2[0] + bias2[2], gg1 = p2[1] + bias2[2]; \
    float go0 = p3[0] + bias2[3], go1 = p3[1] + bias2[3]; \
    c2a = sigm(gf0) * c2a + sigm(gi0) * tanh_f(gg0); \
    c2b = sigm(gf1) * c2b + sigm(gi1) * tanh_f(gg1); \
    float h20 = sigm(go0) * tanh_f(c2a); \
    float h21 = sigm(go1) * tanh_f(c2b); \
    if (lane < 16) { \
      h2b[prv][wb] = (_Float16)h20; \
      h2b[prv][wb + 8] = (_Float16)h21; \
    } \
    if (DOPROJ) { \
      float q0 = h20 * wo, q1 = h21 * wo; \
      q0 += __shfl_xor(q0, 1); q1 += __shfl_xor(q1, 1); \
      q0 += __shfl_xor(q0, 2); q1 += __shfl_xor(q1, 2); \
      q0 += __shfl_xor(q0, 4); q1 += __shfl_xor(q1, 4); \
      q0 += __shfl_xor(q0, 8); q1 += __shfl_xor(q1, 8); \
      if (lane == 0) { \
        opart[w * MB + 0] = q0; \
        opart[w * MB + 1] = q1; \
      } \
    } } while (0)

  for (int k = 0; k < NITER; ++k) {
    const int cur = k & 1;
    const int prv = cur ^ 1;

    if (k < TT) {
      // ---- encoder: mixed-order regions (anti-phase across SIMD partners)
      const float ex0 = (float)xs[k * MB + 0];
      const float ex1 = (float)xs[k * MB + 1];
      if (w < 4) {
        CELL1(ex0, ex1);
      } else if (k >= 1) {
        CELL2(false);
      }
      __syncthreads();  // B1
      __builtin_amdgcn_sched_barrier(0);
      if (w < 4) {
        if (k >= 1) CELL2(false);
      } else {
        CELL1(ex0, ex1);
      }
    } else {
      // ---- future: sequential (x-feedback needs all-wave h2 first)
      CELL2(true);
      __syncthreads();  // B1: opart complete
      __builtin_amdgcn_sched_barrier(0);
      float s0 = bo, s1 = bo;
#pragma unroll
      for (int p = 0; p < 8; ++p) {
        s0 += opart[p * MB + 0];
        s1 += opart[p * MB + 1];
      }
      if (w == 0 && lane < MB) out[(b0g + lane) * NFUT + (k - TT)] = (lane == 0) ? s0 : s1;
      if (k <= NITER - 2) CELL1(s0, s1);
    }
    __syncthreads();  // B2: publish h1(k), h2(k-1)
    __builtin_amdgcn_sched_barrier(0);
  }
}

extern "C" void kernel_launch(void* const* d_in, const int* in_sizes, int n_in,
                              void* d_out, int out_size, void* d_ws, size_t ws_size,
                              hipStream_t stream) {
  const float* x     = (const float*)d_in[0];
  const float* W_ih1 = (const float*)d_in[1];
  const float* b_ih1 = (const float*)d_in[2];
  const float* W_hh1 = (const float*)d_in[3];
  const float* b_hh1 = (const float*)d_in[4];
  const float* W_ih2 = (const float*)d_in[5];
  const float* b_ih2 = (const float*)d_in[6];
  const float* W_hh2 = (const float*)d_in[7];
  const float* b_hh2 = (const float*)d_in[8];
  const float* W_out = (const float*)d_in[9];
  const float* b_out = (const float*)d_in[10];
  (void)in_sizes; (void)n_in; (void)out_size; (void)d_ws; (void)ws_size;

  lstm_kernel<<<dim3(NBLK), dim3(512), 0, stream>>>(
      x, W_ih1, b_ih1, W_hh1, b_hh1, W_ih2, b_ih2, W_hh2, b_hh2, W_out, b_out,
      (float*)d_out);
}